// Round 8
// baseline (273.614 us; speedup 1.0000x reference)
//
#include <hip/hip_runtime.h>
#include <math.h>

#define NROWS   32768
#define CDIM    256
#define KCODES  1024
#define ZQ_ELEMS 8388608   // 32*256*32*32

typedef short  bshort8 __attribute__((ext_vector_type(8)));   // 8 bf16 (4 VGPRs)
typedef float  f32x4   __attribute__((ext_vector_type(4)));

// ---- ws layout (floats) ----
#define ESQ_OFF   0          // 1024
#define ZSQH_OFF  1024       // 2*32768 (zsq half-sums)
#define TB_OFF    66560      // 4*32768 best
#define TS_OFF    197632     // 4*32768 second
#define TI_OFF    328704     // 4*32768 best idx (int)
#define IDX_OFF   459776     // 32768 (int)
#define LIST_OFF  492544     // 32768 (int)
#define CNT_OFF   525312     // 1 int
#define ACC_OFF   525313     // 1 float
#define BHI_OFF   525328     // 131072 uints (16B aligned)
#define BLO_OFF   656400     // 131072 uints

// d_out scratch: cbT (1 MB) at out0, consumed by rescan before gather overwrites.

#define MARGIN_ABS 1.0e-4f   // tie-safe: ulp(dist~256)=3.05e-5 + 2*dist_err(~2e-6) < 1e-4

__device__ __forceinline__ ushort f2bf(float f) {
    union { float f; uint u; } v; v.f = f;
    uint lsb = (v.u >> 16) & 1u;
    return (ushort)((v.u + 0x7fffu + lsb) >> 16);
}
__device__ __forceinline__ float bf2f(ushort b) {
    union { uint u; float f; } v; v.u = ((uint)b) << 16;
    return v.f;
}

// ================= prep: packB (16x16x32 frags, hi/lo) + esq + cbT =================
__global__ __launch_bounds__(256) void prep_kernel(const float* __restrict__ cb,
                                                   uint* __restrict__ Bhi, uint* __restrict__ Blo,
                                                   float* __restrict__ esq,
                                                   float* __restrict__ cbT) {
    const int blk = blockIdx.x, tid = threadIdx.x;
    if (blk < 128) {
        // F = (ct*8+ks)*64+lane ; elem j -> cb[ct*16+(lane&15)][ks*32+(lane>>4)*8+j]
        int F = blk * 256 + tid;
        int ct = F >> 9, ks = (F >> 6) & 7, ln = F & 63;
        int code = ct * 16 + (ln & 15);
        int k0 = ks * 32 + ((ln >> 4) << 3);
        const float* p = cb + (size_t)code * CDIM + k0;
        float4 va = *(const float4*)p;
        float4 vb = *(const float4*)(p + 4);
        float v[8] = {va.x, va.y, va.z, va.w, vb.x, vb.y, vb.z, vb.w};
        uint h[4], l[4];
#pragma unroll
        for (int d = 0; d < 4; ++d) {
            ushort h0 = f2bf(v[2*d]);   float r0 = v[2*d]   - bf2f(h0);
            ushort h1 = f2bf(v[2*d+1]); float r1 = v[2*d+1] - bf2f(h1);
            h[d] = (uint)h0 | ((uint)h1 << 16);
            l[d] = (uint)f2bf(r0) | ((uint)f2bf(r1) << 16);
        }
        *(uint4*)(Bhi + (size_t)F * 4) = make_uint4(h[0], h[1], h[2], h[3]);
        *(uint4*)(Blo + (size_t)F * 4) = make_uint4(l[0], l[1], l[2], l[3]);
    } else if (blk < 132) {
        // e_sq with numpy pairwise semantics
        int k = (blk - 128) * 256 + tid;
        const float* p = cb + (size_t)k * CDIM;
        float half_[2];
        for (int h = 0; h < 2; ++h) {
            const float* q = p + h * 128;
            float r8[8];
#pragma unroll
            for (int j = 0; j < 8; ++j) { float v = q[j]; r8[j] = __fmul_rn(v, v); }
            for (int i = 8; i < 128; i += 8) {
#pragma unroll
                for (int j = 0; j < 8; ++j) {
                    float v = q[i + j];
                    r8[j] = __fadd_rn(r8[j], __fmul_rn(v, v));
                }
            }
            half_[h] = __fadd_rn(__fadd_rn(__fadd_rn(r8[0], r8[1]), __fadd_rn(r8[2], r8[3])),
                                 __fadd_rn(__fadd_rn(r8[4], r8[5]), __fadd_rn(r8[6], r8[7])));
        }
        esq[k] = __fadd_rn(half_[0], half_[1]);
    } else {
        // cbT[k*1024 + code] = cb[code][k]
        int base = (blk - 132) * 4096 + tid;
#pragma unroll
        for (int i = 0; i < 16; ++i) {
            int idx = base + i * 256;
            cbT[idx] = cb[(size_t)(idx & 1023) * CDIM + (idx >> 10)];
        }
    }
}

// ================= main: A-LDS-resident, B via global_load_lds per-wave dbuf =================
// grid 512 (1 block/CU, 2 rounds). Block: 64 rows x 1024 codes; wave w owns codes [w*256,+256).
// Hot loop barrier-free: per-wave counted s_waitcnt vmcnt(8).
__global__ __launch_bounds__(256, 1) void main_mfma(const float* __restrict__ z,
                                                    const uint* __restrict__ Bhi,
                                                    const uint* __restrict__ Blo,
                                                    const float* __restrict__ esq,
                                                    float* __restrict__ zsqh,
                                                    float* __restrict__ tb, float* __restrict__ ts,
                                                    int* __restrict__ ti) {
    __shared__ uint a_hi[8][4][64][4];        // 32 KB  [ks][rt][lane][dw]
    __shared__ uint a_lo[8][4][64][4];        // 32 KB
    __shared__ uint b_lds[4][2][8][64][4];    // 64 KB  [wave][buf][c*2+{hi,lo}][lane][dw]
    __shared__ float esq_s[1024];             // 4 KB
    __shared__ float zsq_s[64];

    const int tid  = threadIdx.x;
    const int rg   = blockIdx.x;
    const int b    = rg >> 4;
    const int hw0  = (rg & 15) << 6;
    const int w    = tid >> 6;
    const int lane = tid & 63;

    // stage esq
#pragma unroll
    for (int i = 0; i < 4; ++i) esq_s[i * 256 + tid] = esq[i * 256 + tid];

    // ---------- prologue: stage z chunks, zsq (numpy order), pack A frags ----------
    {
        float* zt = (float*)&b_lds[0][0][0][0][0];   // [32][68] chunk scratch (8.5 KB, aliased)
        float r8[8];
        const int zhalf = tid >> 6;
        const int zrow  = tid & 63;
        const int prt   = tid >> 6;
        const int prow  = (lane & 15) + prt * 16;
        const int pkb   = (lane >> 4) << 3;

        for (int kc = 0; kc < 8; ++kc) {
            __syncthreads();
#pragma unroll
            for (int p = 0; p < 2; ++p) {
                int fidx = p * 256 + tid;
                int cl = fidx >> 4, h4 = fidx & 15;
                float4 v = *(const float4*)(z + ((size_t)(b * 256 + kc * 32 + cl) << 10) + hw0 + h4 * 4);
                *(float4*)&zt[cl * 68 + h4 * 4] = v;
            }
            __syncthreads();
            if (zhalf < 2 && (kc >> 2) == zhalf) {
#pragma unroll
                for (int g = 0; g < 4; ++g)
#pragma unroll
                    for (int j = 0; j < 8; ++j) {
                        float v = zt[(g * 8 + j) * 68 + zrow];
                        float sq = __fmul_rn(v, v);
                        r8[j] = ((kc & 3) == 0 && g == 0) ? sq : __fadd_rn(r8[j], sq);
                    }
            }
            uint hh[4], ll[4];
#pragma unroll
            for (int d = 0; d < 4; ++d) {
                float v0 = zt[(pkb + 2*d)     * 68 + prow];
                float v1 = zt[(pkb + 2*d + 1) * 68 + prow];
                ushort x0 = f2bf(v0); float q0 = v0 - bf2f(x0);
                ushort x1 = f2bf(v1); float q1 = v1 - bf2f(x1);
                hh[d] = (uint)x0 | ((uint)x1 << 16);
                ll[d] = (uint)f2bf(q0) | ((uint)f2bf(q1) << 16);
            }
            *(uint4*)&a_hi[kc][prt][lane][0] = make_uint4(hh[0], hh[1], hh[2], hh[3]);
            *(uint4*)&a_lo[kc][prt][lane][0] = make_uint4(ll[0], ll[1], ll[2], ll[3]);
        }
        __syncthreads();
        if (zhalf < 2) {
            float hs = __fadd_rn(__fadd_rn(__fadd_rn(r8[0], r8[1]), __fadd_rn(r8[2], r8[3])),
                                 __fadd_rn(__fadd_rn(r8[4], r8[5]), __fadd_rn(r8[6], r8[7])));
            zt[zhalf * 64 + zrow] = hs;
            zsqh[zhalf * NROWS + rg * 64 + zrow] = hs;
        }
        __syncthreads();
        if (tid < 64) zsq_s[tid] = __fadd_rn(zt[tid], zt[64 + tid]);
        __syncthreads();
    }

#define GLDS(SRC, DST) __builtin_amdgcn_global_load_lds(                          \
        (const __attribute__((address_space(1))) void*)(SRC),                     \
        (__attribute__((address_space(3))) void*)(DST), 16, 0, 0)

    auto stage = [&](int t) {
        const int ks = t & 7, cg = t >> 3, buf = t & 1;
#pragma unroll
        for (int c = 0; c < 4; ++c) {
            int ct = w * 16 + cg * 4 + c;
            size_t F = ((size_t)(ct * 8 + ks) * 64 + lane);
            GLDS(Bhi + F * 4, &b_lds[w][buf][c * 2 + 0][0][0]);
            GLDS(Blo + F * 4, &b_lds[w][buf][c * 2 + 1][0][0]);
        }
    };

    float best[16], sec[16]; int bidx[16];
#pragma unroll
    for (int s = 0; s < 16; ++s) { best[s] = INFINITY; sec[s] = INFINITY; bidx[s] = 0; }

    f32x4 acc[4][4];

    // drain prologue stores so vmcnt counting sees only GLDS
    asm volatile("s_waitcnt vmcnt(0)" ::: "memory");
    stage(0);

    for (int t = 0; t < 32; ++t) {
        const int ks = t & 7, cg = t >> 3, buf = t & 1;
        if (ks == 0) {
#pragma unroll
            for (int rt = 0; rt < 4; ++rt)
#pragma unroll
                for (int c = 0; c < 4; ++c) acc[rt][c] = (f32x4){0.f, 0.f, 0.f, 0.f};
        }
        if (t < 31) {
            stage(t + 1);
            asm volatile("s_waitcnt vmcnt(8)" ::: "memory");   // stage(t) complete, stage(t+1) in flight
        } else {
            asm volatile("s_waitcnt vmcnt(0)" ::: "memory");
        }
        __builtin_amdgcn_sched_barrier(0);

        {
            bshort8 bh[4], bl[4];
#pragma unroll
            for (int c = 0; c < 4; ++c) {
                bh[c] = *(const bshort8*)&b_lds[w][buf][c * 2 + 0][lane][0];
                bl[c] = *(const bshort8*)&b_lds[w][buf][c * 2 + 1][lane][0];
            }
#pragma unroll
            for (int rt = 0; rt < 4; ++rt) {
                bshort8 ah = *(const bshort8*)&a_hi[ks][rt][lane][0];
                bshort8 al = *(const bshort8*)&a_lo[ks][rt][lane][0];
#pragma unroll
                for (int c = 0; c < 4; ++c) {
                    acc[rt][c] = __builtin_amdgcn_mfma_f32_16x16x32_bf16(al, bh[c], acc[rt][c], 0, 0, 0);
                    acc[rt][c] = __builtin_amdgcn_mfma_f32_16x16x32_bf16(ah, bl[c], acc[rt][c], 0, 0, 0);
                    acc[rt][c] = __builtin_amdgcn_mfma_f32_16x16x32_bf16(ah, bh[c], acc[rt][c], 0, 0, 0);
                }
            }
        }

        if (ks == 7) {
            // epilogue for this cg: dists + top-2 (codes ascending per lane)
            const int g = lane >> 4, cl = lane & 15;
#pragma unroll
            for (int c = 0; c < 4; ++c) {
                int ct = w * 16 + cg * 4 + c;
                int code = ct * 16 + cl;
                float es = esq_s[code];
#pragma unroll
                for (int rt = 0; rt < 4; ++rt)
#pragma unroll
                    for (int reg = 0; reg < 4; ++reg) {
                        int row_l = rt * 16 + g * 4 + reg;
                        float t1 = __fadd_rn(zsq_s[row_l], es);
                        float dd = __fadd_rn(t1, __fmul_rn(-2.0f, acc[rt][c][reg]));
                        int s = rt * 4 + reg;
                        if (dd < best[s]) { sec[s] = best[s]; best[s] = dd; bidx[s] = code; }
                        else if (dd < sec[s]) sec[s] = dd;
                    }
            }
        }
    }
#undef GLDS

    // cross-lane merge over the 16 col-lanes
#pragma unroll
    for (int mk = 1; mk <= 8; mk <<= 1) {
#pragma unroll
        for (int s = 0; s < 16; ++s) {
            float ob = __shfl_xor(best[s], mk, 64);
            float os = __shfl_xor(sec[s],  mk, 64);
            int   oi = __shfl_xor(bidx[s], mk, 64);
            float mx = fmaxf(best[s], ob);
            sec[s] = fminf(fminf(sec[s], os), mx);
            if (ob < best[s] || (ob == best[s] && oi < bidx[s])) { best[s] = ob; bidx[s] = oi; }
        }
    }
    if ((lane & 15) == 0) {
        const int g = lane >> 4;
#pragma unroll
        for (int s = 0; s < 16; ++s) {
            int rt = s >> 2, reg = s & 3;
            int row = rg * 64 + rt * 16 + g * 4 + reg;
            size_t o = (size_t)w * NROWS + row;
            tb[o] = best[s]; ts[o] = sec[s]; ti[o] = bidx[s];
        }
    }
}

// ================= finalize: merge 4 quarters, flag near-ties =================
__global__ __launch_bounds__(256) void finalize_kernel(const float* __restrict__ tb,
                                                       const float* __restrict__ ts,
                                                       const int* __restrict__ ti,
                                                       float* __restrict__ oidxf,
                                                       int* __restrict__ idx_i,
                                                       int* __restrict__ list,
                                                       int* __restrict__ count) {
    int row = blockIdx.x * 256 + threadIdx.x;
    float b = INFINITY, s = INFINITY; int bi = 0;
#pragma unroll
    for (int q = 0; q < 4; ++q) {
        float v = tb[(size_t)q * NROWS + row];
        int  vi = ti[(size_t)q * NROWS + row];
        if (v < b || (v == b && vi < bi)) { s = b; b = v; bi = vi; }
        else s = fminf(s, v);
        s = fminf(s, ts[(size_t)q * NROWS + row]);
    }
    if (s <= b + MARGIN_ABS) {
        int p = atomicAdd(count, 1);
        list[p] = row;
    } else {
        oidxf[row] = (float)bi;
        idx_i[row] = bi;
    }
}

// ================= rescan: exact fp32 chain; 16 rows/block, 4 rows/wave =================
__global__ __launch_bounds__(256) void rescan_kernel(const float* __restrict__ z,
                                                     const float* __restrict__ cbT,
                                                     const float* __restrict__ esq,
                                                     const float* __restrict__ zsqh,
                                                     const int* __restrict__ list,
                                                     const int* __restrict__ count,
                                                     float* __restrict__ oidxf,
                                                     int* __restrict__ idx_i) {
    __shared__ float ct_lds[8][1024];   // 32 KB
    __shared__ float z_lds[16][256];    // 16 KB
    __shared__ float esq_lds[1024];     // 4 KB
    const int tid = threadIdx.x, lane = tid & 63, w = tid >> 6;
    const int n = count[0];
#pragma unroll
    for (int i = 0; i < 4; ++i) esq_lds[i * 256 + tid] = esq[i * 256 + tid];

    for (int base = blockIdx.x * 16; base < n; base += gridDim.x * 16) {
        __syncthreads();
        for (int i = 0; i < 16; ++i) {
            int gi = base + i;
            int row = list[gi < n ? gi : n - 1];
            z_lds[i][tid] = z[((size_t)(row >> 10) * 256 + tid) * 1024 + (row & 1023)];
        }

        float acc[4][16];
#pragma unroll
        for (int r = 0; r < 4; ++r)
#pragma unroll
            for (int j = 0; j < 16; ++j) acc[r][j] = 0.0f;

        for (int kt = 0; kt < 32; ++kt) {
            __syncthreads();
#pragma unroll
            for (int u = 0; u < 8; ++u) {
                float4 v = *(const float4*)(cbT + (size_t)(kt * 8 + u) * 1024 + tid * 4);
                *(float4*)&ct_lds[u][tid * 4] = v;
            }
            __syncthreads();
#pragma unroll
            for (int k8 = 0; k8 < 8; ++k8) {
                float4 c[4];
#pragma unroll
                for (int j = 0; j < 4; ++j)
                    c[j] = *(const float4*)&ct_lds[k8][lane * 16 + j * 4];
#pragma unroll
                for (int r = 0; r < 4; ++r) {
                    float zv = z_lds[w * 4 + r][kt * 8 + k8];
                    acc[r][0]  = fmaf(zv, c[0].x, acc[r][0]);
                    acc[r][1]  = fmaf(zv, c[0].y, acc[r][1]);
                    acc[r][2]  = fmaf(zv, c[0].z, acc[r][2]);
                    acc[r][3]  = fmaf(zv, c[0].w, acc[r][3]);
                    acc[r][4]  = fmaf(zv, c[1].x, acc[r][4]);
                    acc[r][5]  = fmaf(zv, c[1].y, acc[r][5]);
                    acc[r][6]  = fmaf(zv, c[1].z, acc[r][6]);
                    acc[r][7]  = fmaf(zv, c[1].w, acc[r][7]);
                    acc[r][8]  = fmaf(zv, c[2].x, acc[r][8]);
                    acc[r][9]  = fmaf(zv, c[2].y, acc[r][9]);
                    acc[r][10] = fmaf(zv, c[2].z, acc[r][10]);
                    acc[r][11] = fmaf(zv, c[2].w, acc[r][11]);
                    acc[r][12] = fmaf(zv, c[3].x, acc[r][12]);
                    acc[r][13] = fmaf(zv, c[3].y, acc[r][13]);
                    acc[r][14] = fmaf(zv, c[3].z, acc[r][14]);
                    acc[r][15] = fmaf(zv, c[3].w, acc[r][15]);
                }
            }
        }

#pragma unroll
        for (int r = 0; r < 4; ++r) {
            int slot = w * 4 + r;
            int gi = base + slot;
            int row = list[gi < n ? gi : n - 1];
            float zs = __fadd_rn(zsqh[row], zsqh[NROWS + row]);
            float bv = INFINITY; int bi = 0;
#pragma unroll
            for (int j = 0; j < 16; ++j) {
                int code = lane * 16 + j;
                float dd = __fadd_rn(__fadd_rn(zs, esq_lds[code]), __fmul_rn(-2.0f, acc[r][j]));
                if (dd < bv) { bv = dd; bi = code; }
            }
#pragma unroll
            for (int mk = 1; mk <= 32; mk <<= 1) {
                float ob = __shfl_xor(bv, mk, 64);
                int   oi = __shfl_xor(bi, mk, 64);
                if (ob < bv || (ob == bv && oi < bi)) { bv = ob; bi = oi; }
            }
            if (lane == 0 && gi < n) { oidxf[row] = (float)bi; idx_i[row] = bi; }
        }
    }
}

// ================= gather z_q + loss =================
__global__ __launch_bounds__(256) void gather_kernel(const float* __restrict__ z,
                                                     const float* __restrict__ cb,
                                                     const int* __restrict__ idx_i,
                                                     float* __restrict__ out0,
                                                     float* __restrict__ accum) {
    int tid   = threadIdx.x;
    int blk   = blockIdx.x;
    int b     = blk >> 5;
    int chunk = (blk >> 3) & 3;
    int cgrp  = blk & 7;
    int hw = chunk * 256 + tid;
    int n  = b * 1024 + hw;
    int code = idx_i[n];
    const float* cp = cb + (size_t)code * CDIM + cgrp * 32;
    float lsum = 0.0f;
    size_t base = (size_t)b * 262144 + hw + (size_t)(cgrp * 32) * 1024;
#pragma unroll
    for (int cc = 0; cc < 8; ++cc) {
        float4 q4 = *(const float4*)(cp + cc * 4);
        float qv[4] = {q4.x, q4.y, q4.z, q4.w};
#pragma unroll
        for (int u = 0; u < 4; ++u) {
            size_t off = base + (size_t)(cc * 4 + u) * 1024;
            float zv = z[off];
            out0[off] = qv[u];
            float dfr = zv - qv[u];
            lsum = fmaf(dfr, dfr, lsum);
        }
    }
#pragma unroll
    for (int mm = 32; mm >= 1; mm >>= 1) lsum += __shfl_down(lsum, mm, 64);
    __shared__ float red[4];
    int wv = tid >> 6, ln = tid & 63;
    if (ln == 0) red[wv] = lsum;
    __syncthreads();
    if (tid == 0) atomicAdd(accum, (red[0] + red[1]) + (red[2] + red[3]));
}

__global__ void finalize_loss(const float* __restrict__ accum, float* __restrict__ out_loss) {
    out_loss[0] = accum[0] * (1.25f / 8388608.0f);
}

extern "C" void kernel_launch(void* const* d_in, const int* in_sizes, int n_in,
                              void* d_out, int out_size, void* d_ws, size_t ws_size,
                              hipStream_t stream) {
    const float* z  = (const float*)d_in[0];   // [32,256,32,32]
    const float* cb = (const float*)d_in[1];   // [1024,256]

    float* ws   = (float*)d_ws;
    float* esq  = ws + ESQ_OFF;
    float* zsqh = ws + ZSQH_OFF;
    float* tb   = ws + TB_OFF;
    float* ts   = ws + TS_OFF;
    int*   ti   = (int*)(ws + TI_OFF);
    int*   idx_i = (int*)(ws + IDX_OFF);
    int*   list = (int*)(ws + LIST_OFF);
    int*   cnt  = (int*)(ws + CNT_OFF);
    float* accum = ws + ACC_OFF;
    uint*  Bhi  = (uint*)(ws + BHI_OFF);
    uint*  Blo  = (uint*)(ws + BLO_OFF);

    float* out0     = (float*)d_out;
    float* out_loss = out0 + ZQ_ELEMS;
    float* out_idxf = out0 + ZQ_ELEMS + 1;

    float* cbT = out0;   // 1 MB scratch in z_q region; rescan consumes before gather overwrites

    hipMemsetAsync(cnt, 0, 8, stream);  // count + accum

    prep_kernel <<<196, 256, 0, stream>>>(cb, Bhi, Blo, esq, cbT);
    main_mfma   <<<512, 256, 0, stream>>>(z, Bhi, Blo, esq, zsqh, tb, ts, ti);
    finalize_kernel<<<128, 256, 0, stream>>>(tb, ts, ti, out_idxf, idx_i, list, cnt);
    rescan_kernel<<<512, 256, 0, stream>>>(z, cbT, esq, zsqh, list, cnt, out_idxf, idx_i);
    gather_kernel<<<1024, 256, 0, stream>>>(z, cb, idx_i, out0, accum);
    finalize_loss<<<1, 1, 0, stream>>>(accum, out_loss);
}

// Round 9
// 227.574 us; speedup vs baseline: 1.2023x; 1.2023x over previous
//
#include <hip/hip_runtime.h>
#include <math.h>

#define NROWS   32768
#define CDIM    256
#define KCODES  1024
#define ZQ_ELEMS 8388608   // 32*256*32*32

typedef short  bshort8 __attribute__((ext_vector_type(8)));   // 8 bf16 (4 VGPRs)
typedef float  f32x4   __attribute__((ext_vector_type(4)));

// ---- ws layout (floats) ----
#define ESQ_OFF   0          // 1024
#define ZSQH_OFF  1024       // 2*32768 (zsq half-sums)
#define IDX_OFF   459776     // 32768 (int)
#define LIST_OFF  492544     // 32768 (int)
#define CNT_OFF   525312     // 1 int
#define ACC_OFF   525313     // 1 float
#define BHI_OFF   525328     // 131072 uints (16B aligned)
#define BLO_OFF   656400     // 131072 uints

// d_out scratch: cbT (1 MB) at out0, consumed by rescan before gather overwrites.

#define MARGIN_ABS 1.0e-4f   // tie-safe: ulp(dist~256)=3.05e-5 + 2*dist_err(~2e-5) < 1e-4

__device__ __forceinline__ ushort f2bf(float f) {
    union { float f; uint u; } v; v.f = f;
    uint lsb = (v.u >> 16) & 1u;
    return (ushort)((v.u + 0x7fffu + lsb) >> 16);
}
__device__ __forceinline__ float bf2f(ushort b) {
    union { uint u; float f; } v; v.u = ((uint)b) << 16;
    return v.f;
}

// ================= prep: packB (16x16x32 frags, hi/lo) + esq + cbT =================
__global__ __launch_bounds__(256) void prep_kernel(const float* __restrict__ cb,
                                                   uint* __restrict__ Bhi, uint* __restrict__ Blo,
                                                   float* __restrict__ esq,
                                                   float* __restrict__ cbT) {
    const int blk = blockIdx.x, tid = threadIdx.x;
    if (blk < 128) {
        // F = (ct*8+ks)*64+lane ; elem j -> cb[ct*16+(lane&15)][ks*32+(lane>>4)*8+j]
        int F = blk * 256 + tid;
        int ct = F >> 9, ks = (F >> 6) & 7, ln = F & 63;
        int code = ct * 16 + (ln & 15);
        int k0 = ks * 32 + ((ln >> 4) << 3);
        const float* p = cb + (size_t)code * CDIM + k0;
        float4 va = *(const float4*)p;
        float4 vb = *(const float4*)(p + 4);
        float v[8] = {va.x, va.y, va.z, va.w, vb.x, vb.y, vb.z, vb.w};
        uint h[4], l[4];
#pragma unroll
        for (int d = 0; d < 4; ++d) {
            ushort h0 = f2bf(v[2*d]);   float r0 = v[2*d]   - bf2f(h0);
            ushort h1 = f2bf(v[2*d+1]); float r1 = v[2*d+1] - bf2f(h1);
            h[d] = (uint)h0 | ((uint)h1 << 16);
            l[d] = (uint)f2bf(r0) | ((uint)f2bf(r1) << 16);
        }
        *(uint4*)(Bhi + (size_t)F * 4) = make_uint4(h[0], h[1], h[2], h[3]);
        *(uint4*)(Blo + (size_t)F * 4) = make_uint4(l[0], l[1], l[2], l[3]);
    } else if (blk < 132) {
        // e_sq with numpy pairwise semantics
        int k = (blk - 128) * 256 + tid;
        const float* p = cb + (size_t)k * CDIM;
        float half_[2];
        for (int h = 0; h < 2; ++h) {
            const float* q = p + h * 128;
            float r8[8];
#pragma unroll
            for (int j = 0; j < 8; ++j) { float v = q[j]; r8[j] = __fmul_rn(v, v); }
            for (int i = 8; i < 128; i += 8) {
#pragma unroll
                for (int j = 0; j < 8; ++j) {
                    float v = q[i + j];
                    r8[j] = __fadd_rn(r8[j], __fmul_rn(v, v));
                }
            }
            half_[h] = __fadd_rn(__fadd_rn(__fadd_rn(r8[0], r8[1]), __fadd_rn(r8[2], r8[3])),
                                 __fadd_rn(__fadd_rn(r8[4], r8[5]), __fadd_rn(r8[6], r8[7])));
        }
        esq[k] = __fadd_rn(half_[0], half_[1]);
    } else {
        // cbT[k*1024 + code] = cb[code][k]
        int base = (blk - 132) * 4096 + tid;
#pragma unroll
        for (int i = 0; i < 16; ++i) {
            int idx = base + i * 256;
            cbT[idx] = cb[(size_t)(idx & 1023) * CDIM + (idx >> 10)];
        }
    }
}

// ================= main: 8 waves, A-LDS-resident, B via per-wave GLDS dbuf ==============
// grid 512 (1 block/CU, 2 rounds; 8 waves = 2/SIMD). Block: 64 rows x 1024 codes.
// Wave w owns codes [w*128, w*128+128). Hot loop barrier-free, counted vmcnt(4).
// Finalize (8-way merge + near-tie flagging) is done in-kernel.
__global__ __launch_bounds__(512, 2) void main_mfma(const float* __restrict__ z,
                                                    const uint* __restrict__ Bhi,
                                                    const uint* __restrict__ Blo,
                                                    const float* __restrict__ esq,
                                                    float* __restrict__ zsqh,
                                                    float* __restrict__ oidxf,
                                                    int* __restrict__ idx_i,
                                                    int* __restrict__ list,
                                                    int* __restrict__ count) {
    __shared__ uint a_hi[8][4][64][4];        // 32 KB  [ks][rt][lane][dw]
    __shared__ uint a_lo[8][4][64][4];        // 32 KB
    __shared__ uint b_lds[8][2][4][64][4];    // 64 KB  [wave][buf][2ct x {hi,lo}][lane][dw]
    __shared__ float esq_s[1024];             // 4 KB
    __shared__ float zsq_s[64];
    __shared__ float m_b[8][64];              // 2 KB cross-wave merge
    __shared__ float m_s[8][64];              // 2 KB
    __shared__ int   m_i[8][64];              // 2 KB

    const int tid  = threadIdx.x;
    const int rg   = blockIdx.x;
    const int b    = rg >> 4;
    const int hw0  = (rg & 15) << 6;
    const int w    = tid >> 6;
    const int lane = tid & 63;

    // stage esq (512 thr x 2)
    {
        float2 e2 = *(const float2*)(esq + tid * 2);
        esq_s[tid * 2] = e2.x; esq_s[tid * 2 + 1] = e2.y;
    }

    // ---------- prologue: stage z chunks, zsq (numpy order), pack A frags ----------
    {
        float* zt = (float*)&b_lds[0][0][0][0][0];   // [32][68] scratch (8.5 KB, aliased)
        float r8[8];
        const int zhalf = tid >> 6;          // (tid<128): 0/1 k-half workers
        const int zrow  = tid & 63;
        const int prt   = tid >> 6;          // (tid<256): pack rt role
        const int plane = tid & 63;
        const int prow  = (plane & 15) + prt * 16;
        const int pkb   = (plane >> 4) << 3;

        for (int kc = 0; kc < 8; ++kc) {
            __syncthreads();
            {   // 32 dims x 64 rows, one float4 per thread, coalesced
                int cl = tid >> 4, h4 = tid & 15;
                float4 v = *(const float4*)(z + ((size_t)(b * 256 + kc * 32 + cl) << 10) + hw0 + h4 * 4);
                *(float4*)&zt[cl * 68 + h4 * 4] = v;
            }
            __syncthreads();
            if (tid < 128 && (kc >> 2) == zhalf) {
#pragma unroll
                for (int g = 0; g < 4; ++g)
#pragma unroll
                    for (int j = 0; j < 8; ++j) {
                        float v = zt[(g * 8 + j) * 68 + zrow];
                        float sq = __fmul_rn(v, v);
                        r8[j] = ((kc & 3) == 0 && g == 0) ? sq : __fadd_rn(r8[j], sq);
                    }
            }
            if (tid < 256) {
                uint hh[4], ll[4];
#pragma unroll
                for (int d = 0; d < 4; ++d) {
                    float v0 = zt[(pkb + 2*d)     * 68 + prow];
                    float v1 = zt[(pkb + 2*d + 1) * 68 + prow];
                    ushort x0 = f2bf(v0); float q0 = v0 - bf2f(x0);
                    ushort x1 = f2bf(v1); float q1 = v1 - bf2f(x1);
                    hh[d] = (uint)x0 | ((uint)x1 << 16);
                    ll[d] = (uint)f2bf(q0) | ((uint)f2bf(q1) << 16);
                }
                *(uint4*)&a_hi[kc][prt][plane][0] = make_uint4(hh[0], hh[1], hh[2], hh[3]);
                *(uint4*)&a_lo[kc][prt][plane][0] = make_uint4(ll[0], ll[1], ll[2], ll[3]);
            }
        }
        __syncthreads();
        if (tid < 128) {
            float hs = __fadd_rn(__fadd_rn(__fadd_rn(r8[0], r8[1]), __fadd_rn(r8[2], r8[3])),
                                 __fadd_rn(__fadd_rn(r8[4], r8[5]), __fadd_rn(r8[6], r8[7])));
            zt[zhalf * 64 + zrow] = hs;
            zsqh[zhalf * NROWS + rg * 64 + zrow] = hs;
        }
        __syncthreads();
        if (tid < 64) zsq_s[tid] = __fadd_rn(zt[tid], zt[64 + tid]);
        __syncthreads();
    }

#define GLDS(SRC, DST) __builtin_amdgcn_global_load_lds(                          \
        (const __attribute__((address_space(1))) void*)(SRC),                     \
        (__attribute__((address_space(3))) void*)(DST), 16, 0, 0)

    auto stage = [&](int t) {
        const int cg = t >> 3, ks = t & 7, buf = t & 1;
#pragma unroll
        for (int c = 0; c < 2; ++c) {
            int ct = w * 8 + cg * 2 + c;
            size_t F = ((size_t)(ct * 8 + ks) * 64 + lane);
            GLDS(Bhi + F * 4, &b_lds[w][buf][c * 2 + 0][0][0]);
            GLDS(Blo + F * 4, &b_lds[w][buf][c * 2 + 1][0][0]);
        }
    };

    float best[16], sec[16]; int bidx[16];
#pragma unroll
    for (int s = 0; s < 16; ++s) { best[s] = INFINITY; sec[s] = INFINITY; bidx[s] = 0; }

    f32x4 acc[4][2];

    // drain prologue vmem so vmcnt counting sees only GLDS
    asm volatile("s_waitcnt vmcnt(0)" ::: "memory");
    stage(0);

    for (int t = 0; t < 32; ++t) {
        const int ks = t & 7, cg = t >> 3, buf = t & 1;
        if (ks == 0) {
#pragma unroll
            for (int rt = 0; rt < 4; ++rt)
#pragma unroll
                for (int c = 0; c < 2; ++c) acc[rt][c] = (f32x4){0.f, 0.f, 0.f, 0.f};
        }
        if (t < 31) {
            stage(t + 1);
            asm volatile("s_waitcnt vmcnt(4)" ::: "memory");   // stage(t) done, stage(t+1) in flight
        } else {
            asm volatile("s_waitcnt vmcnt(0)" ::: "memory");
        }
        __builtin_amdgcn_sched_barrier(0);

        {
            bshort8 bh[2], bl[2];
#pragma unroll
            for (int c = 0; c < 2; ++c) {
                bh[c] = *(const bshort8*)&b_lds[w][buf][c * 2 + 0][lane][0];
                bl[c] = *(const bshort8*)&b_lds[w][buf][c * 2 + 1][lane][0];
            }
#pragma unroll
            for (int rt = 0; rt < 4; ++rt) {
                bshort8 ah = *(const bshort8*)&a_hi[ks][rt][lane][0];
                bshort8 al = *(const bshort8*)&a_lo[ks][rt][lane][0];
#pragma unroll
                for (int c = 0; c < 2; ++c) {
                    acc[rt][c] = __builtin_amdgcn_mfma_f32_16x16x32_bf16(al, bh[c], acc[rt][c], 0, 0, 0);
                    acc[rt][c] = __builtin_amdgcn_mfma_f32_16x16x32_bf16(ah, bl[c], acc[rt][c], 0, 0, 0);
                    acc[rt][c] = __builtin_amdgcn_mfma_f32_16x16x32_bf16(ah, bh[c], acc[rt][c], 0, 0, 0);
                }
            }
        }

        if (ks == 7) {
            // epilogue for this cg: dists + top-2 (codes ascending per lane over cg,c)
            const int g = lane >> 4, cl = lane & 15;
#pragma unroll
            for (int c = 0; c < 2; ++c) {
                int ct = w * 8 + cg * 2 + c;
                int code = ct * 16 + cl;
                float es = esq_s[code];
#pragma unroll
                for (int rt = 0; rt < 4; ++rt)
#pragma unroll
                    for (int reg = 0; reg < 4; ++reg) {
                        int row_l = rt * 16 + g * 4 + reg;
                        float t1 = __fadd_rn(zsq_s[row_l], es);
                        float dd = __fadd_rn(t1, __fmul_rn(-2.0f, acc[rt][c][reg]));
                        int s = rt * 4 + reg;
                        if (dd < best[s]) { sec[s] = best[s]; best[s] = dd; bidx[s] = code; }
                        else if (dd < sec[s]) sec[s] = dd;
                    }
            }
        }
    }
#undef GLDS

    // intra-wave merge over the 16 col-lanes
#pragma unroll
    for (int mk = 1; mk <= 8; mk <<= 1) {
#pragma unroll
        for (int s = 0; s < 16; ++s) {
            float ob = __shfl_xor(best[s], mk, 64);
            float os = __shfl_xor(sec[s],  mk, 64);
            int   oi = __shfl_xor(bidx[s], mk, 64);
            float mx = fmaxf(best[s], ob);
            sec[s] = fminf(fminf(sec[s], os), mx);
            if (ob < best[s] || (ob == best[s] && oi < bidx[s])) { best[s] = ob; bidx[s] = oi; }
        }
    }
    // per-wave candidates -> LDS
    if ((lane & 15) == 0) {
        const int g = lane >> 4;
#pragma unroll
        for (int s = 0; s < 16; ++s) {
            int rt = s >> 2, reg = s & 3;
            int row_l = rt * 16 + g * 4 + reg;
            m_b[w][row_l] = best[s]; m_s[w][row_l] = sec[s]; m_i[w][row_l] = bidx[s];
        }
    }
    __syncthreads();
    // cross-wave merge + near-tie flagging (inline finalize)
    if (tid < 64) {
        float bb = INFINITY, ss = INFINITY; int bi = 0;
#pragma unroll
        for (int q = 0; q < 8; ++q) {
            float v = m_b[q][tid]; int vi = m_i[q][tid];
            if (v < bb || (v == bb && vi < bi)) { ss = bb; bb = v; bi = vi; }
            else ss = fminf(ss, v);
            ss = fminf(ss, m_s[q][tid]);
        }
        int row = rg * 64 + tid;
        if (ss <= bb + MARGIN_ABS) {
            int p = atomicAdd(count, 1);
            list[p] = row;
        } else {
            oidxf[row] = (float)bi;
            idx_i[row] = bi;
        }
    }
}

// ================= rescan: exact fp32 chain; 16 rows/block, 4 rows/wave =================
__global__ __launch_bounds__(256) void rescan_kernel(const float* __restrict__ z,
                                                     const float* __restrict__ cbT,
                                                     const float* __restrict__ esq,
                                                     const float* __restrict__ zsqh,
                                                     const int* __restrict__ list,
                                                     const int* __restrict__ count,
                                                     float* __restrict__ oidxf,
                                                     int* __restrict__ idx_i) {
    __shared__ float ct_lds[8][1024];   // 32 KB
    __shared__ float z_lds[16][256];    // 16 KB
    __shared__ float esq_lds[1024];     // 4 KB
    const int tid = threadIdx.x, lane = tid & 63, w = tid >> 6;
    const int n = count[0];
#pragma unroll
    for (int i = 0; i < 4; ++i) esq_lds[i * 256 + tid] = esq[i * 256 + tid];

    for (int base = blockIdx.x * 16; base < n; base += gridDim.x * 16) {
        __syncthreads();
        for (int i = 0; i < 16; ++i) {
            int gi = base + i;
            int row = list[gi < n ? gi : n - 1];
            z_lds[i][tid] = z[((size_t)(row >> 10) * 256 + tid) * 1024 + (row & 1023)];
        }

        float acc[4][16];
#pragma unroll
        for (int r = 0; r < 4; ++r)
#pragma unroll
            for (int j = 0; j < 16; ++j) acc[r][j] = 0.0f;

        for (int kt = 0; kt < 32; ++kt) {
            __syncthreads();
#pragma unroll
            for (int u = 0; u < 8; ++u) {
                float4 v = *(const float4*)(cbT + (size_t)(kt * 8 + u) * 1024 + tid * 4);
                *(float4*)&ct_lds[u][tid * 4] = v;
            }
            __syncthreads();
#pragma unroll
            for (int k8 = 0; k8 < 8; ++k8) {
                float4 c[4];
#pragma unroll
                for (int j = 0; j < 4; ++j)
                    c[j] = *(const float4*)&ct_lds[k8][lane * 16 + j * 4];
#pragma unroll
                for (int r = 0; r < 4; ++r) {
                    float zv = z_lds[w * 4 + r][kt * 8 + k8];
                    acc[r][0]  = fmaf(zv, c[0].x, acc[r][0]);
                    acc[r][1]  = fmaf(zv, c[0].y, acc[r][1]);
                    acc[r][2]  = fmaf(zv, c[0].z, acc[r][2]);
                    acc[r][3]  = fmaf(zv, c[0].w, acc[r][3]);
                    acc[r][4]  = fmaf(zv, c[1].x, acc[r][4]);
                    acc[r][5]  = fmaf(zv, c[1].y, acc[r][5]);
                    acc[r][6]  = fmaf(zv, c[1].z, acc[r][6]);
                    acc[r][7]  = fmaf(zv, c[1].w, acc[r][7]);
                    acc[r][8]  = fmaf(zv, c[2].x, acc[r][8]);
                    acc[r][9]  = fmaf(zv, c[2].y, acc[r][9]);
                    acc[r][10] = fmaf(zv, c[2].z, acc[r][10]);
                    acc[r][11] = fmaf(zv, c[2].w, acc[r][11]);
                    acc[r][12] = fmaf(zv, c[3].x, acc[r][12]);
                    acc[r][13] = fmaf(zv, c[3].y, acc[r][13]);
                    acc[r][14] = fmaf(zv, c[3].z, acc[r][14]);
                    acc[r][15] = fmaf(zv, c[3].w, acc[r][15]);
                }
            }
        }

#pragma unroll
        for (int r = 0; r < 4; ++r) {
            int slot = w * 4 + r;
            int gi = base + slot;
            int row = list[gi < n ? gi : n - 1];
            float zs = __fadd_rn(zsqh[row], zsqh[NROWS + row]);
            float bv = INFINITY; int bi = 0;
#pragma unroll
            for (int j = 0; j < 16; ++j) {
                int code = lane * 16 + j;
                float dd = __fadd_rn(__fadd_rn(zs, esq_lds[code]), __fmul_rn(-2.0f, acc[r][j]));
                if (dd < bv) { bv = dd; bi = code; }
            }
#pragma unroll
            for (int mk = 1; mk <= 32; mk <<= 1) {
                float ob = __shfl_xor(bv, mk, 64);
                int   oi = __shfl_xor(bi, mk, 64);
                if (ob < bv || (ob == bv && oi < bi)) { bv = ob; bi = oi; }
            }
            if (lane == 0 && gi < n) { oidxf[row] = (float)bi; idx_i[row] = bi; }
        }
    }
}

// ================= gather z_q + loss =================
__global__ __launch_bounds__(256) void gather_kernel(const float* __restrict__ z,
                                                     const float* __restrict__ cb,
                                                     const int* __restrict__ idx_i,
                                                     float* __restrict__ out0,
                                                     float* __restrict__ accum) {
    int tid   = threadIdx.x;
    int blk   = blockIdx.x;
    int b     = blk >> 5;
    int chunk = (blk >> 3) & 3;
    int cgrp  = blk & 7;
    int hw = chunk * 256 + tid;
    int n  = b * 1024 + hw;
    int code = idx_i[n];
    const float* cp = cb + (size_t)code * CDIM + cgrp * 32;
    float lsum = 0.0f;
    size_t base = (size_t)b * 262144 + hw + (size_t)(cgrp * 32) * 1024;
#pragma unroll
    for (int cc = 0; cc < 8; ++cc) {
        float4 q4 = *(const float4*)(cp + cc * 4);
        float qv[4] = {q4.x, q4.y, q4.z, q4.w};
#pragma unroll
        for (int u = 0; u < 4; ++u) {
            size_t off = base + (size_t)(cc * 4 + u) * 1024;
            float zv = z[off];
            out0[off] = qv[u];
            float dfr = zv - qv[u];
            lsum = fmaf(dfr, dfr, lsum);
        }
    }
#pragma unroll
    for (int mm = 32; mm >= 1; mm >>= 1) lsum += __shfl_down(lsum, mm, 64);
    __shared__ float red[4];
    int wv = tid >> 6, ln = tid & 63;
    if (ln == 0) red[wv] = lsum;
    __syncthreads();
    if (tid == 0) atomicAdd(accum, (red[0] + red[1]) + (red[2] + red[3]));
}

__global__ void finalize_loss(const float* __restrict__ accum, float* __restrict__ out_loss) {
    out_loss[0] = accum[0] * (1.25f / 8388608.0f);
}

extern "C" void kernel_launch(void* const* d_in, const int* in_sizes, int n_in,
                              void* d_out, int out_size, void* d_ws, size_t ws_size,
                              hipStream_t stream) {
    const float* z  = (const float*)d_in[0];   // [32,256,32,32]
    const float* cb = (const float*)d_in[1];   // [1024,256]

    float* ws   = (float*)d_ws;
    float* esq  = ws + ESQ_OFF;
    float* zsqh = ws + ZSQH_OFF;
    int*   idx_i = (int*)(ws + IDX_OFF);
    int*   list = (int*)(ws + LIST_OFF);
    int*   cnt  = (int*)(ws + CNT_OFF);
    float* accum = ws + ACC_OFF;
    uint*  Bhi  = (uint*)(ws + BHI_OFF);
    uint*  Blo  = (uint*)(ws + BLO_OFF);

    float* out0     = (float*)d_out;
    float* out_loss = out0 + ZQ_ELEMS;
    float* out_idxf = out0 + ZQ_ELEMS + 1;

    float* cbT = out0;   // 1 MB scratch in z_q region; rescan consumes before gather overwrites

    hipMemsetAsync(cnt, 0, 8, stream);  // count + accum

    prep_kernel <<<196, 256, 0, stream>>>(cb, Bhi, Blo, esq, cbT);
    main_mfma   <<<512, 512, 0, stream>>>(z, Bhi, Blo, esq, zsqh, out_idxf, idx_i, list, cnt);
    rescan_kernel<<<512, 256, 0, stream>>>(z, cbT, esq, zsqh, list, cnt, out_idxf, idx_i);
    gather_kernel<<<1024, 256, 0, stream>>>(z, cb, idx_i, out0, accum);
    finalize_loss<<<1, 1, 0, stream>>>(accum, out_loss);
}